// Round 16
// baseline (1712.833 us; speedup 1.0000x reference)
//
#include <hip/hip_runtime.h>
#include <math.h>

namespace {

constexpr int Bc = 4, Tc = 1024, Ec = 768, Hc = 12, Lc = 6;
constexpr int Vc = 32000, FFc = 3072, Mc = Bc * Tc;   // M = 4096
constexpr int QKVN = 3 * Ec;                          // 2304

typedef __bf16 bf16x8 __attribute__((ext_vector_type(8)));
typedef float f32x4 __attribute__((ext_vector_type(4)));

__device__ __forceinline__ unsigned short f2bf(float f) {
  unsigned u = __builtin_bit_cast(unsigned, f);
  u += 0x7FFFu + ((u >> 16) & 1u);
  return (unsigned short)(u >> 16);
}

__device__ __forceinline__ float wave_sum(float v) {
#pragma unroll
  for (int off = 32; off > 0; off >>= 1) v += __shfl_xor(v, off, 64);
  return v;
}
__device__ __forceinline__ float block_sum256(float v, volatile float* red) {
  v = wave_sum(v);
  __syncthreads();
  if ((threadIdx.x & 63) == 0) red[threadIdx.x >> 6] = v;
  __syncthreads();
  return red[0] + red[1] + red[2] + red[3];
}
// online (max,sumexp) merge
__device__ __forceinline__ void omerge(float& m, float& s, float om, float os) {
  if (om > m) { s = s * __expf(m - om) + os; m = om; }
  else        { s = s + os * __expf(om - m); }
}
// raw workgroup barrier with compiler memory fences (no vmcnt(0) drain)
__device__ __forceinline__ void raw_barrier() {
  asm volatile("" ::: "memory");
  __builtin_amdgcn_s_barrier();
  asm volatile("" ::: "memory");
}

// ---------------- embedding ----------------
__global__ __launch_bounds__(256) void embed_k(const int* __restrict__ tokens,
                                               const float* __restrict__ emb,
                                               const float* __restrict__ pet,
                                               float* __restrict__ x) {
  int i = blockIdx.x * 256 + threadIdx.x;
  int m = i / Ec, e = i - m * Ec;
  int tok = tokens[m];
  x[i] = emb[(size_t)tok * Ec + e] + pet[(size_t)(m & (Tc - 1)) * Ec + e];
}

// ---------------- layernorm: fp32 in -> bf16 out ----------------
__global__ __launch_bounds__(256) void ln_k(const float* __restrict__ in,
                                            const float* __restrict__ g,
                                            const float* __restrict__ bb,
                                            unsigned short* __restrict__ outp) {
  __shared__ float red[4];
  int row = blockIdx.x, tid = threadIdx.x;
  const float* xr = in + (size_t)row * Ec;
  float v0 = xr[tid], v1 = xr[tid + 256], v2 = xr[tid + 512];
  float mean = block_sum256(v0 + v1 + v2, red) * (1.0f / 768.0f);
  float d0 = v0 - mean, d1 = v1 - mean, d2 = v2 - mean;
  float var = block_sum256(d0 * d0 + d1 * d1 + d2 * d2, red) * (1.0f / 768.0f);
  float rs = rsqrtf(var + 1e-5f);
  unsigned short* orow = outp + (size_t)row * Ec;
  orow[tid]       = f2bf(d0 * rs * g[tid]       + bb[tid]);
  orow[tid + 256] = f2bf(d1 * rs * g[tid + 256] + bb[tid + 256]);
  orow[tid + 512] = f2bf(d2 * rs * g[tid + 512] + bb[tid + 512]);
}

// ------- weight convert: [K][N] fp32 -> [N][K] bf16, batched -------
__global__ __launch_bounds__(256) void tcvt_k(const float* __restrict__ src,
                                              unsigned short* __restrict__ dst,
                                              int K, int N,
                                              size_t srcBatch, size_t dstBatch) {
  __shared__ float t[64][65];
  const float* s = src + blockIdx.z * srcBatch;
  unsigned short* d = dst + blockIdx.z * dstBatch;
  int k0 = blockIdx.y * 64, n0 = blockIdx.x * 64;
  int tid = threadIdx.x;
#pragma unroll
  for (int i = 0; i < 16; ++i) {
    int rr = (tid >> 6) + i * 4, cc = tid & 63;
    t[rr][cc] = s[(size_t)(k0 + rr) * N + n0 + cc];
  }
  __syncthreads();
#pragma unroll
  for (int i = 0; i < 16; ++i) {
    int rr = (tid >> 6) + i * 4, cc = tid & 63;
    d[(size_t)(n0 + rr) * K + k0 + cc] = f2bf(t[cc][rr]);
  }
}

// ------- wq/wk/wv [L][H][E][HS] fp32 -> fused qkvT [L][2304][768] bf16 -------
__global__ __launch_bounds__(256) void qcvt_k(const float* __restrict__ wq,
                                              const float* __restrict__ wk,
                                              const float* __restrict__ wv,
                                              unsigned short* __restrict__ dst) {
  __shared__ float t[64][65];
  const int which = blockIdx.y / (Lc * Hc);
  const int z = blockIdx.y % (Lc * Hc), l = z / Hc, h = z % Hc;
  const float* src = which == 0 ? wq : (which == 1 ? wk : wv);
  const int k0 = blockIdx.x * 64;
  const int tid = threadIdx.x;
  const float* s = src + ((size_t)z * Ec + k0) * 64;
  unsigned short* d =
      dst + (size_t)l * QKVN * Ec + ((size_t)which * Ec + h * 64) * Ec + k0;
#pragma unroll
  for (int i = 0; i < 16; ++i) {
    int rr = (tid >> 6) + i * 4, cc = tid & 63;
    t[rr][cc] = s[(size_t)rr * 64 + cc];
  }
  __syncthreads();
#pragma unroll
  for (int i = 0; i < 16; ++i) {
    int rr = (tid >> 6) + i * 4, cc = tid & 63;
    d[(size_t)rr * Ec + cc] = f2bf(t[cc][rr]);
  }
}

// ------- MFMA bf16 GEMM, dbuf + counted-vmcnt (T3+T4) + T2 swizzle ----------
// C[M,N] = A[M,K] * Bt[N,K]^T
// MODE: 0 bf16 out; 1 bf16 out+bias+relu; 2 fp32 C+=acc+bias; 3 fp32 out+bias;
//       4 fp32 out+bias + CE-loss partials (m,s) per (row,n-block) -> pbuf.
// BSRC: 0 Bt bf16 [N][K]; 1 B fp32 [K][N] (BM=BN=128 only).
// T2: GLDS dest linear, GLOBAL source col pre-swizzled (col8 ^= row&7); reads
// use byte ^= (row&7)<<4 -> conflict-free (verified: SQ_LDS_BANK_CONFLICT=0).
// GX: >1 -> grid=(GX, N/BN, M/BM/GX), bm-fastest (B dedup for logits).
#define GLDS16(g, l)                                              \
  __builtin_amdgcn_global_load_lds(                               \
      (const __attribute__((address_space(1))) void*)(g),         \
      (__attribute__((address_space(3))) void*)(l), 16, 0, 0)

template <int MODE, int BSRC, int BM, int BN, int GX>
__global__ __launch_bounds__(256) void mgemm_k(
    const unsigned short* __restrict__ A, const void* __restrict__ Bv,
    const float* __restrict__ bias, void* __restrict__ Cv,
    int M, int N, int K, float* __restrict__ pbuf) {
  constexpr int MI = BM / 32, NF = BN / 32;   // m/n frags per wave
  constexpr int TL = BM / 32 + BN / 32;       // GLDS loads per thread per stage
  __shared__ unsigned short AsU[2][BM * 64];
  __shared__ unsigned short BsU[2][BN * 64];
  const int tid = threadIdx.x, lane = tid & 63, wave = tid >> 6;
  int bm, bn;
  if constexpr (GX == 1) {
    bm = blockIdx.y * BM;
    bn = blockIdx.x * BN;
  } else {
    bm = (blockIdx.z * GX + blockIdx.x) * BM;
    bn = blockIdx.y * BN;
  }
  const int wm = (wave >> 1) * (BM / 2), wn = (wave & 1) * (BN / 2);
  const int fr = lane & 15, fq = lane >> 4;
  const int lr8 = lane >> 3, lc8 = (lane & 7) * 8;
  const int sc8 = ((lane & 7) ^ (lr8 & 7)) * 8;  // T2 pre-swizzled source col
  f32x4 acc[MI][NF];
#pragma unroll
  for (int i = 0; i < MI; ++i)
#pragma unroll
    for (int j = 0; j < NF; ++j) acc[i][j] = (f32x4){0.f, 0.f, 0.f, 0.f};

  auto stage = [&](int k0, int pb) {
    {  // A: source col pre-swizzled; LDS dest linear (row&7 == lr8 for all it)
      const unsigned short* g =
          A + (size_t)(bm + wave * (BM / 4) + lr8) * K + k0 + sc8;
      unsigned short* l = &AsU[pb][(wave * (BM / 4) + lr8) * 64 + lc8];
#pragma unroll
      for (int it = 0; it < BM / 32; ++it)
        GLDS16(g + (size_t)(it * 8) * K, l + it * 8 * 64);
    }
    if constexpr (BSRC == 0) {
      const unsigned short* Bt = (const unsigned short*)Bv;
      const unsigned short* g =
          Bt + (size_t)(bn + wave * (BN / 4) + lr8) * K + k0 + sc8;
      unsigned short* l = &BsU[pb][(wave * (BN / 4) + lr8) * 64 + lc8];
#pragma unroll
      for (int it = 0; it < BN / 32; ++it)
        GLDS16(g + (size_t)(it * 8) * K, l + it * 8 * 64);
    } else {
      const float* Bf = (const float*)Bv;
#pragma unroll
      for (int i = 0; i < 8; ++i) {
        int f4 = i * 256 + tid;
        int kk = f4 >> 5, c4 = (f4 & 31) * 4;
        float4 v = *(const float4*)(Bf + (size_t)(k0 + kk) * N + bn + c4);
        BsU[pb][(c4 + 0) * 64 + kk] = f2bf(v.x);
        BsU[pb][(c4 + 1) * 64 + kk] = f2bf(v.y);
        BsU[pb][(c4 + 2) * 64 + kk] = f2bf(v.z);
        BsU[pb][(c4 + 3) * 64 + kk] = f2bf(v.w);
      }
    }
  };

  auto compute = [&](int pb) {
#pragma unroll
    for (int kk = 0; kk < 2; ++kk) {
      bf16x8 af[MI], bfr[NF];
#pragma unroll
      for (int i = 0; i < MI; ++i) {
        int row = wm + i * 16 + fr;
        af[i] = *(const bf16x8*)((char*)AsU[pb] + row * 128 +
                                 ((kk * 64 + fq * 16) ^ ((row & 7) << 4)));
      }
#pragma unroll
      for (int j = 0; j < NF; ++j) {
        int row = wn + j * 16 + fr;
        if constexpr (BSRC == 0)
          bfr[j] = *(const bf16x8*)((char*)BsU[pb] + row * 128 +
                                    ((kk * 64 + fq * 16) ^ ((row & 7) << 4)));
        else
          bfr[j] = *(const bf16x8*)&BsU[pb][row * 64 + kk * 32 + fq * 8];
      }
#pragma unroll
      for (int i = 0; i < MI; ++i)
#pragma unroll
        for (int j = 0; j < NF; ++j)
          acc[i][j] = __builtin_amdgcn_mfma_f32_16x16x32_bf16(af[i], bfr[j],
                                                              acc[i][j], 0, 0, 0);
    }
  };

  const int nk = K >> 6;
  if constexpr (BSRC == 0) {
    // T3+T4: tile t+1's GLDS loads stay in flight across both barriers.
    stage(0, 0);
    for (int t = 0; t < nk; ++t) {
      const int pb = t & 1;
      if (t + 1 < nk) {
        stage((t + 1) << 6, pb ^ 1);
        if constexpr (TL == 8)      asm volatile("s_waitcnt vmcnt(8)" ::: "memory");
        else if constexpr (TL == 6) asm volatile("s_waitcnt vmcnt(6)" ::: "memory");
        else                        asm volatile("s_waitcnt vmcnt(4)" ::: "memory");
      } else {
        asm volatile("s_waitcnt vmcnt(0)" ::: "memory");
      }
      raw_barrier();        // all waves' tile-t data in LDS
      compute(pb);
      raw_barrier();        // all waves done reading buf[pb]
    }
  } else {
    stage(0, 0);
    __syncthreads();
    for (int t = 0; t < nk; ++t) {
      const int pb = t & 1;
      if (t + 1 < nk) stage((t + 1) << 6, pb ^ 1);
      compute(pb);
      __syncthreads();
    }
  }
  if constexpr (MODE == 4) {
    // fp32 out + bias + per-(row, n-block) online softmax partials.
    float* pms = (float*)AsU;   // reuse dead A-tile LDS: [BM][2][2]
    float* C = (float*)Cv;
    float pm_[MI][4], ps_[MI][4];
#pragma unroll
    for (int i = 0; i < MI; ++i) {
      int row0 = bm + wm + i * 16 + fq * 4;
#pragma unroll
      for (int r = 0; r < 4; ++r) {
        float vj[NF];
#pragma unroll
        for (int j = 0; j < NF; ++j) {
          int col = bn + wn + j * 16 + fr;
          float v = acc[i][j][r] + bias[col];
          C[(size_t)(row0 + r) * N + col] = v;
          vj[j] = v;
        }
        float m = vj[0];
#pragma unroll
        for (int j = 1; j < NF; ++j) m = fmaxf(m, vj[j]);
        float s = 0.f;
#pragma unroll
        for (int j = 0; j < NF; ++j) s += __expf(vj[j] - m);
        pm_[i][r] = m;
        ps_[i][r] = s;
      }
    }
#pragma unroll
    for (int off = 1; off <= 8; off <<= 1)
#pragma unroll
      for (int i = 0; i < MI; ++i)
#pragma unroll
        for (int r = 0; r < 4; ++r) {
          float om = __shfl_xor(pm_[i][r], off, 64);
          float os = __shfl_xor(ps_[i][r], off, 64);
          omerge(pm_[i][r], ps_[i][r], om, os);
        }
    if (fr == 0) {
#pragma unroll
      for (int i = 0; i < MI; ++i)
#pragma unroll
        for (int r = 0; r < 4; ++r) {
          int lrow = wm + i * 16 + fq * 4 + r;
          pms[lrow * 4 + (wave & 1) * 2 + 0] = pm_[i][r];
          pms[lrow * 4 + (wave & 1) * 2 + 1] = ps_[i][r];
        }
    }
    __syncthreads();
    if (tid < BM) {
      float m = pms[tid * 4 + 0], s = pms[tid * 4 + 1];
      omerge(m, s, pms[tid * 4 + 2], pms[tid * 4 + 3]);
      size_t pi = ((size_t)(bm + tid) * (N >> 7) + (bn >> 7)) * 2;
      pbuf[pi] = m;
      pbuf[pi + 1] = s;
    }
    return;
  }
#pragma unroll
  for (int i = 0; i < MI; ++i) {
    int row0 = bm + wm + i * 16 + fq * 4;
#pragma unroll
    for (int j = 0; j < NF; ++j) {
      int col = bn + wn + j * 16 + fr;
      float bval = 0.f;
      if constexpr (MODE != 0) bval = bias[col];
#pragma unroll
      for (int r = 0; r < 4; ++r) {
        size_t idx = (size_t)(row0 + r) * N + col;
        float v = acc[i][j][r];
        if constexpr (MODE == 0) {
          ((unsigned short*)Cv)[idx] = f2bf(v);
        } else if constexpr (MODE == 1) {
          ((unsigned short*)Cv)[idx] = f2bf(fmaxf(v + bval, 0.f));
        } else if constexpr (MODE == 2) {
          float* C = (float*)Cv;
          C[idx] = C[idx] + v + bval;
        } else {
          ((float*)Cv)[idx] = v + bval;
        }
      }
    }
  }
}

// ------------- MFMA flash attention, QBLK=128, K/V double-buffered -----------
// ONE barrier per tile. Ones-column denominator in o[mi][4]. exp2 domain.
// T13 defer via PER-LANE bound check: the cross-lane max reduce runs only
// when some value exceeds m_run+8 (rare after tile 0).
__global__ __launch_bounds__(256) void fattn2_k(const unsigned short* __restrict__ qkv,
                                                unsigned short* __restrict__ att) {
  __shared__ unsigned short Ks[2][64 * 64];
  __shared__ unsigned short Vt[2][80 * 64];
  __shared__ unsigned short Pb[4][16 * 72];
  const int bh = blockIdx.y;
  const int b = bh / Hc, h = bh % Hc;
  const int qb = gridDim.x - 1 - blockIdx.x;   // heavy blocks dispatched first
  const int q0 = qb * 128;
  const int tid = threadIdx.x, lane = tid & 63, w = tid >> 6;
  const int fr = lane & 15, fq = lane >> 4;
  const size_t base = (size_t)b * Tc * QKVN + h * 64;
  const int r0 = tid >> 3, c0 = (tid & 7) * 8;          // K staging map
  const int s2 = (tid & 31) * 2, c0v = (tid >> 5) * 8;  // V staging map
  const float SC = 0.125f * 1.44269504f;                // scale * log2(e)

  bf16x8 aq[2][2];
#pragma unroll
  for (int mi = 0; mi < 2; ++mi) {
    const unsigned short* qp =
        qkv + base + (size_t)(q0 + w * 32 + mi * 16 + fr) * QKVN + fq * 8;
    aq[mi][0] = *(const bf16x8*)qp;
    aq[mi][1] = *(const bf16x8*)(qp + 32);
  }
  f32x4 o[2][5];
  float m_run[2][4];
#pragma unroll
  for (int mi = 0; mi < 2; ++mi)
#pragma unroll
    for (int n = 0; n < 5; ++n) o[mi][n] = (f32x4){0.f, 0.f, 0.f, 0.f};
#pragma unroll
  for (int mi = 0; mi < 2; ++mi)
#pragma unroll
    for (int r = 0; r < 4; ++r) m_run[mi][r] = -INFINITY;

  {  // init Vt rows 64..79 for BOTH buffers (constant rows)
#pragma unroll
    for (int bx = 0; bx < 2; ++bx) {
      unsigned* vt32 = (unsigned*)(Vt[bx] + 64 * 64);
      vt32[tid] = (tid < 32) ? 0x3F803F80u : 0u;   // row 64 = ones
      vt32[tid + 256] = 0u;                        // rows 72..79
    }
  }

  const int nt = 2 * qb + 2;
  uint4 pk0, pk1, pv0, pv1;
  auto loadt = [&](int s0) {
    const unsigned short* kg = qkv + base + Ec + (size_t)(s0 + r0) * QKVN + c0;
    pk0 = *(const uint4*)kg;
    pk1 = *(const uint4*)(kg + (size_t)32 * QKVN);
    const unsigned short* vg =
        qkv + base + 2 * Ec + (size_t)(s0 + s2) * QKVN + c0v;
    pv0 = *(const uint4*)vg;
    pv1 = *(const uint4*)(vg + QKVN);
  };
  auto writet = [&](int bx) {
    *(uint4*)((char*)Ks[bx] + (r0 * 128 + ((c0 * 2) ^ ((r0 & 7) << 4)))) = pk0;
    const int r1 = r0 + 32;
    *(uint4*)((char*)Ks[bx] + (r1 * 128 + ((c0 * 2) ^ ((r1 & 7) << 4)))) = pk1;
    const unsigned short* p0 = (const unsigned short*)&pv0;
    const unsigned short* p1 = (const unsigned short*)&pv1;
#pragma unroll
    for (int j = 0; j < 8; ++j) {
      int hs = c0v + j;
      unsigned pk = (unsigned)p0[j] | ((unsigned)p1[j] << 16);
      *(unsigned*)((char*)Vt[bx] + (hs * 128 + ((s2 * 2) ^ ((hs & 7) << 4)))) = pk;
    }
  };

  loadt(0);
  writet(0);
  __syncthreads();

  for (int it = 0; it < nt; ++it) {
    const int s0 = it * 64;
    const int pb = it & 1;
    if (it + 1 < nt) loadt(s0 + 64);   // T14: issue next-tile loads early

    f32x4 s[2][4];
#pragma unroll
    for (int mi = 0; mi < 2; ++mi)
#pragma unroll
      for (int n = 0; n < 4; ++n) s[mi][n] = (f32x4){0.f, 0.f, 0.f, 0.f};
    __builtin_amdgcn_s_setprio(1);
#pragma unroll
    for (int ss = 0; ss < 2; ++ss)
#pragma unroll
      for (int n = 0; n < 4; ++n) {
        int row = n * 16 + fr;
        bf16x8 kb = *(const bf16x8*)(
            (char*)Ks[pb] + (row * 128 + ((ss * 64 + fq * 16) ^ ((row & 7) << 4))));
#pragma unroll
        for (int mi = 0; mi < 2; ++mi)
          s[mi][n] = __builtin_amdgcn_mfma_f32_16x16x32_bf16(aq[mi][ss], kb,
                                                             s[mi][n], 0, 0, 0);
      }
    __builtin_amdgcn_s_setprio(0);

#pragma unroll
    for (int mi = 0; mi < 2; ++mi) {
      const int qlo = q0 + w * 32 + mi * 16;
      const bool need_mask = (s0 + 63 > qlo);
#pragma unroll
      for (int n = 0; n < 4; ++n) {
        int scol = s0 + n * 16 + fr;
#pragma unroll
        for (int r = 0; r < 4; ++r) {
          float v = s[mi][n][r] * SC;
          if (need_mask && scol > qlo + fq * 4 + r) v = -INFINITY;
          s[mi][n][r] = v;
        }
      }
      // per-lane defer check: skip cross-lane reduce when bound holds
      bool ok = true;
#pragma unroll
      for (int n = 0; n < 4; ++n)
#pragma unroll
        for (int r = 0; r < 4; ++r)
          ok &= (s[mi][n][r] <= m_run[mi][r] + 8.f);
      if (!__all(ok)) {   // rare: full reduce + rescale
        float mt[4];
#pragma unroll
        for (int r = 0; r < 4; ++r)
          mt[r] = fmaxf(fmaxf(s[mi][0][r], s[mi][1][r]),
                        fmaxf(s[mi][2][r], s[mi][3][r]));
#pragma unroll
        for (int off = 1; off <= 8; off <<= 1)
#pragma unroll
          for (int r = 0; r < 4; ++r)
            mt[r] = fmaxf(mt[r], __shfl_xor(mt[r], off, 64));
        float alpha[4];
#pragma unroll
        for (int r = 0; r < 4; ++r) {
          float mn = fmaxf(m_run[mi][r], mt[r]);
          alpha[r] = exp2f(m_run[mi][r] - mn);
          m_run[mi][r] = mn;
        }
#pragma unroll
        for (int n = 0; n < 5; ++n)       // includes denominator column
#pragma unroll
          for (int r = 0; r < 4; ++r) o[mi][n][r] *= alpha[r];
      }
#pragma unroll
      for (int n = 0; n < 4; ++n)
#pragma unroll
        for (int r = 0; r < 4; ++r)
          Pb[w][(fq * 4 + r) * 72 + n * 16 + fr] =
              f2bf(exp2f(s[mi][n][r] - m_run[mi][r]));
      __builtin_amdgcn_s_setprio(1);
#pragma unroll
      for (int ss = 0; ss < 2; ++ss) {
        bf16x8 pa = *(const bf16x8*)&Pb[w][fr * 72 + ss * 32 + fq * 8];
#pragma unroll
        for (int n = 0; n < 5; ++n) {     // n=4: ones column -> row-sum (l)
          int row = n * 16 + fr;
          bf16x8 vb = *(const bf16x8*)(
              (char*)Vt[pb] + (row * 128 + ((ss * 64 + fq * 16) ^ ((row & 7) << 4))));
          o[mi][n] = __builtin_amdgcn_mfma_f32_16x16x32_bf16(pa, vb, o[mi][n],
                                                             0, 0, 0);
        }
      }
      __builtin_amdgcn_s_setprio(0);
    }

    if (it + 1 < nt) writet(pb ^ 1);   // fill other buffer
    __syncthreads();                   // ONE barrier per tile
  }
  // epilogue: l for row (fq,r) lives at lane fq*16 (col 64); broadcast per group
#pragma unroll
  for (int mi = 0; mi < 2; ++mi)
#pragma unroll
    for (int r = 0; r < 4; ++r) {
      const float l = __shfl(o[mi][4][r], lane & 48, 64);
      const float inv = 1.0f / l;
      const int qrow = q0 + w * 32 + mi * 16 + fq * 4 + r;
      unsigned short* orow = att + ((size_t)(b * Tc + qrow)) * Ec + h * 64;
#pragma unroll
      for (int n = 0; n < 4; ++n) orow[n * 16 + fr] = f2bf(o[mi][n][r] * inv);
    }
}

// ---------------- loss from fused partials ----------------
__global__ __launch_bounds__(256) void lossfin_k(const float* __restrict__ pbuf,
                                                 const float* __restrict__ logits,
                                                 const int* __restrict__ targets,
                                                 float* __restrict__ rowloss) {
  const int row = blockIdx.x * 4 + (threadIdx.x >> 6);
  const int lane = threadIdx.x & 63;
  const float* p = pbuf + (size_t)row * 500;   // 250 (m,s) pairs
  float m = -INFINITY, s = 0.f;
  for (int j = lane; j < 250; j += 64) omerge(m, s, p[j * 2], p[j * 2 + 1]);
#pragma unroll
  for (int off = 32; off > 0; off >>= 1) {
    float om = __shfl_xor(m, off, 64), os = __shfl_xor(s, off, 64);
    omerge(m, s, om, os);
  }
  if (lane == 0) {
    float lt = logits[(size_t)row * Vc + targets[row]];
    rowloss[row] = -(lt - m - logf(s));
  }
}

// ---------------- fallback: online-softmax cross-entropy --------------------
__global__ __launch_bounds__(256) void loss_k(const float* __restrict__ logits,
                                              const int* __restrict__ targets,
                                              float* __restrict__ rowloss) {
  __shared__ float redm[4], reds[4];
  const int row = blockIdx.x, tid = threadIdx.x;
  const f32x4* lr4 = (const f32x4*)(logits + (size_t)row * Vc);
  float m = -INFINITY, s = 0.f;
  for (int j = tid; j < Vc / 4; j += 256) {
    f32x4 v = __builtin_nontemporal_load(lr4 + j);
    float m0 = fmaxf(fmaxf(v[0], v[1]), fmaxf(v[2], v[3]));
    float nm = fmaxf(m, m0);
    s = s * __expf(m - nm) + __expf(v[0] - nm) + __expf(v[1] - nm) +
        __expf(v[2] - nm) + __expf(v[3] - nm);
    m = nm;
  }
#pragma unroll
  for (int off = 32; off; off >>= 1) {
    float om = __shfl_xor(m, off, 64), os = __shfl_xor(s, off, 64);
    float nm = fmaxf(m, om);
    s = s * __expf(m - nm) + os * __expf(om - nm);
    m = nm;
  }
  if ((tid & 63) == 0) { redm[tid >> 6] = m; reds[tid >> 6] = s; }
  __syncthreads();
  if (tid == 0) {
    float M2 = redm[0], S2 = reds[0];
#pragma unroll
    for (int w = 1; w < 4; ++w) {
      float om = redm[w], os = reds[w];
      float nm = fmaxf(M2, om);
      S2 = S2 * __expf(M2 - nm) + os * __expf(om - nm);
      M2 = nm;
    }
    float lt = logits[(size_t)row * Vc + targets[row]];
    rowloss[row] = -(lt - M2 - logf(S2));
  }
}

__global__ __launch_bounds__(1024) void lossred_k(const float* __restrict__ rowloss,
                                                  float* __restrict__ outp) {
  __shared__ float red[16];
  float s = 0.f;
  for (int i = threadIdx.x; i < Mc; i += 1024) s += rowloss[i];
  s = wave_sum(s);
  if ((threadIdx.x & 63) == 0) red[threadIdx.x >> 6] = s;
  __syncthreads();
  if (threadIdx.x == 0) {
    float tot = 0.f;
#pragma unroll
    for (int i = 0; i < 16; ++i) tot += red[i];
    outp[0] = tot * (1.0f / (float)Mc);
  }
}

}  // namespace

extern "C" void kernel_launch(void* const* d_in, const int* in_sizes, int n_in,
                              void* d_out, int out_size, void* d_ws, size_t ws_size,
                              hipStream_t stream) {
  const int*   tokens  = (const int*)d_in[0];
  const int*   targets = (const int*)d_in[1];
  const float* tok_emb = (const float*)d_in[2];
  const float* pet     = (const float*)d_in[3];
  const float* wq      = (const float*)d_in[4];
  const float* wk      = (const float*)d_in[5];
  const float* wv      = (const float*)d_in[6];
  const float* w_proj  = (const float*)d_in[7];
  const float* b_proj  = (const float*)d_in[8];
  const float* ln1_g   = (const float*)d_in[9];
  const float* ln1_b   = (const float*)d_in[10];
  const float* ln2_g   = (const float*)d_in[11];
  const float* ln2_b   = (const float*)d_in[12];
  const float* w_ff1   = (const float*)d_in[13];
  const float* b_ff1   = (const float*)d_in[14];
  const float* w_ff2   = (const float*)d_in[15];
  const float* b_ff2   = (const float*)d_in[16];
  const float* lnf_g   = (const float*)d_in[17];
  const float* lnf_b   = (const float*)d_in[18];
  const float* w_out   = (const float*)d_in[19];
  const float* b_out   = (const float*)d_in[20];

  float* out = (float*)d_out;
  char* ob = (char*)d_out;
  // scratch inside dead logits region of d_out (write-before-read per call)
  unsigned short* qkvA  = (unsigned short*)(ob + 0);          // [M][2304] bf16
  unsigned short* attA  = (unsigned short*)(ob + 18874368);   // [M][768]  bf16
  unsigned short* ffhA  = (unsigned short*)(ob + 25165824);   // [M][3072] bf16
  unsigned short* qkvT  = (unsigned short*)(ob + 50331648);   // [L][2304][768]
  unsigned short* projT = (unsigned short*)(ob + 71565312);   // [L][768][768]
  unsigned short* ff1T  = (unsigned short*)(ob + 78643200);   // [L][3072][768]
  unsigned short* ff2T  = (unsigned short*)(ob + 106954752);  // [L][768][3072]
  char* wb = (char*)d_ws;
  float* x = (float*)wb;                                       // 12,582,912 B
  unsigned short* hbuf = (unsigned short*)(wb + 12582912);     //  6,291,456 B
  float* rowloss = (float*)(wb + 18874368);                    //     16,384 B
  unsigned short* woutT = (unsigned short*)(wb + 18890752);    // 49,152,000 B
  float* pbuf = (float*)(wb + 68042752);                       //  8,192,000 B
  const bool wfit = ws_size >= (size_t)18890752 + 49152000;
  const bool pfit = ws_size >= (size_t)68042752 + 8192000;

  qcvt_k<<<dim3(12, 3 * Lc * Hc), 256, 0, stream>>>(wq, wk, wv, qkvT);
  tcvt_k<<<dim3(12, 12, 6), 256, 0, stream>>>(w_proj, projT, 768, 768,
                                              (size_t)589824, (size_t)589824);
  tcvt_k<<<dim3(48, 12, 6), 256, 0, stream>>>(w_ff1, ff1T, 768, 3072,
                                              (size_t)768 * 3072, (size_t)768 * 3072);
  tcvt_k<<<dim3(12, 48, 6), 256, 0, stream>>>(w_ff2, ff2T, 3072, 768,
                                              (size_t)768 * 3072, (size_t)768 * 3072);
  if (wfit)
    tcvt_k<<<dim3(500, 12, 1), 256, 0, stream>>>(w_out, woutT, 768, 32000, 0, 0);

  embed_k<<<(Mc * Ec) / 256, 256, 0, stream>>>(tokens, tok_emb, pet, x);

  for (int l = 0; l < Lc; ++l) {
    ln_k<<<Mc, 256, 0, stream>>>(x, ln1_g + (size_t)l * Ec, ln1_b + (size_t)l * Ec, hbuf);
    // qkv: 128x64 tile, grid 1152
    mgemm_k<0, 0, 128, 64, 1><<<dim3(36, 32), 256, 0, stream>>>(
        hbuf, qkvT + (size_t)l * QKVN * Ec, nullptr, qkvA, Mc, QKVN, Ec, nullptr);
    fattn2_k<<<dim3(Tc / 128, Bc * Hc), 256, 0, stream>>>(qkvA, attA);
    // proj: 64x64 tile, grid 768 = 3/CU exact
    mgemm_k<2, 0, 64, 64, 1><<<dim3(12, 64), 256, 0, stream>>>(
        attA, projT + (size_t)l * Ec * Ec, b_proj + (size_t)l * Ec, x, Mc, Ec, Ec, nullptr);
    ln_k<<<Mc, 256, 0, stream>>>(x, ln2_g + (size_t)l * Ec, ln2_b + (size_t)l * Ec, hbuf);
    // ff1: 128x64 tile, grid 1536 = 6/CU exact
    mgemm_k<1, 0, 128, 64, 1><<<dim3(48, 32), 256, 0, stream>>>(
        hbuf, ff1T + (size_t)l * Ec * FFc, b_ff1 + (size_t)l * FFc, ffhA, Mc, FFc, Ec, nullptr);
    // ff2: 64x64 tile, grid 768 = 3/CU exact
    mgemm_k<2, 0, 64, 64, 1><<<dim3(12, 64), 256, 0, stream>>>(
        ffhA, ff2T + (size_t)l * Ec * FFc, b_ff2 + (size_t)l * Ec, x, Mc, Ec, FFc, nullptr);
  }
  ln_k<<<Mc, 256, 0, stream>>>(x, lnf_g, lnf_b, hbuf);
  // logits GEMM: round-15 config (bm-fastest dedup, T2, PIPE=2, 128x128)
  // + fused CE partials when pbuf fits
  if (wfit && pfit) {
    mgemm_k<4, 0, 128, 128, 32><<<dim3(32, 250, 1), 256, 0, stream>>>(
        hbuf, woutT, b_out, out, Mc, Vc, Ec, pbuf);
    lossfin_k<<<Mc / 4, 256, 0, stream>>>(pbuf, out, targets, rowloss);
  } else if (wfit) {
    mgemm_k<3, 0, 128, 128, 32><<<dim3(32, 250, 1), 256, 0, stream>>>(
        hbuf, woutT, b_out, out, Mc, Vc, Ec, nullptr);
    loss_k<<<Mc, 256, 0, stream>>>(out, targets, rowloss);
  } else {
    mgemm_k<3, 1, 128, 128, 1><<<dim3(250, 32), 256, 0, stream>>>(
        hbuf, w_out, b_out, out, Mc, Vc, Ec, nullptr);
    loss_k<<<Mc, 256, 0, stream>>>(out, targets, rowloss);
  }
  lossred_k<<<1, 1024, 0, stream>>>(rowloss, out + (size_t)Mc * Vc);
}

// Round 17
// 1589.207 us; speedup vs baseline: 1.0778x; 1.0778x over previous
//
#include <hip/hip_runtime.h>
#include <math.h>

namespace {

constexpr int Bc = 4, Tc = 1024, Ec = 768, Hc = 12, Lc = 6;
constexpr int Vc = 32000, FFc = 3072, Mc = Bc * Tc;   // M = 4096
constexpr int QKVN = 3 * Ec;                          // 2304

typedef __bf16 bf16x8 __attribute__((ext_vector_type(8)));
typedef float f32x4 __attribute__((ext_vector_type(4)));

__device__ __forceinline__ unsigned short f2bf(float f) {
  unsigned u = __builtin_bit_cast(unsigned, f);
  u += 0x7FFFu + ((u >> 16) & 1u);
  return (unsigned short)(u >> 16);
}

__device__ __forceinline__ float wave_sum(float v) {
#pragma unroll
  for (int off = 32; off > 0; off >>= 1) v += __shfl_xor(v, off, 64);
  return v;
}
__device__ __forceinline__ float block_sum256(float v, volatile float* red) {
  v = wave_sum(v);
  __syncthreads();
  if ((threadIdx.x & 63) == 0) red[threadIdx.x >> 6] = v;
  __syncthreads();
  return red[0] + red[1] + red[2] + red[3];
}
// raw workgroup barrier with compiler memory fences (no vmcnt(0) drain)
__device__ __forceinline__ void raw_barrier() {
  asm volatile("" ::: "memory");
  __builtin_amdgcn_s_barrier();
  asm volatile("" ::: "memory");
}

// ---------------- embedding ----------------
__global__ __launch_bounds__(256) void embed_k(const int* __restrict__ tokens,
                                               const float* __restrict__ emb,
                                               const float* __restrict__ pet,
                                               float* __restrict__ x) {
  int i = blockIdx.x * 256 + threadIdx.x;
  int m = i / Ec, e = i - m * Ec;
  int tok = tokens[m];
  x[i] = emb[(size_t)tok * Ec + e] + pet[(size_t)(m & (Tc - 1)) * Ec + e];
}

// ---------------- layernorm: fp32 in -> bf16 out ----------------
__global__ __launch_bounds__(256) void ln_k(const float* __restrict__ in,
                                            const float* __restrict__ g,
                                            const float* __restrict__ bb,
                                            unsigned short* __restrict__ outp) {
  __shared__ float red[4];
  int row = blockIdx.x, tid = threadIdx.x;
  const float* xr = in + (size_t)row * Ec;
  float v0 = xr[tid], v1 = xr[tid + 256], v2 = xr[tid + 512];
  float mean = block_sum256(v0 + v1 + v2, red) * (1.0f / 768.0f);
  float d0 = v0 - mean, d1 = v1 - mean, d2 = v2 - mean;
  float var = block_sum256(d0 * d0 + d1 * d1 + d2 * d2, red) * (1.0f / 768.0f);
  float rs = rsqrtf(var + 1e-5f);
  unsigned short* orow = outp + (size_t)row * Ec;
  orow[tid]       = f2bf(d0 * rs * g[tid]       + bb[tid]);
  orow[tid + 256] = f2bf(d1 * rs * g[tid + 256] + bb[tid + 256]);
  orow[tid + 512] = f2bf(d2 * rs * g[tid + 512] + bb[tid + 512]);
}

// ------- weight convert: [K][N] fp32 -> [N][K] bf16, batched -------
__global__ __launch_bounds__(256) void tcvt_k(const float* __restrict__ src,
                                              unsigned short* __restrict__ dst,
                                              int K, int N,
                                              size_t srcBatch, size_t dstBatch) {
  __shared__ float t[64][65];
  const float* s = src + blockIdx.z * srcBatch;
  unsigned short* d = dst + blockIdx.z * dstBatch;
  int k0 = blockIdx.y * 64, n0 = blockIdx.x * 64;
  int tid = threadIdx.x;
#pragma unroll
  for (int i = 0; i < 16; ++i) {
    int rr = (tid >> 6) + i * 4, cc = tid & 63;
    t[rr][cc] = s[(size_t)(k0 + rr) * N + n0 + cc];
  }
  __syncthreads();
#pragma unroll
  for (int i = 0; i < 16; ++i) {
    int rr = (tid >> 6) + i * 4, cc = tid & 63;
    d[(size_t)(n0 + rr) * K + k0 + cc] = f2bf(t[cc][rr]);
  }
}

// ------- wq/wk/wv [L][H][E][HS] fp32 -> fused qkvT [L][2304][768] bf16 -------
__global__ __launch_bounds__(256) void qcvt_k(const float* __restrict__ wq,
                                              const float* __restrict__ wk,
                                              const float* __restrict__ wv,
                                              unsigned short* __restrict__ dst) {
  __shared__ float t[64][65];
  const int which = blockIdx.y / (Lc * Hc);
  const int z = blockIdx.y % (Lc * Hc), l = z / Hc, h = z % Hc;
  const float* src = which == 0 ? wq : (which == 1 ? wk : wv);
  const int k0 = blockIdx.x * 64;
  const int tid = threadIdx.x;
  const float* s = src + ((size_t)z * Ec + k0) * 64;
  unsigned short* d =
      dst + (size_t)l * QKVN * Ec + ((size_t)which * Ec + h * 64) * Ec + k0;
#pragma unroll
  for (int i = 0; i < 16; ++i) {
    int rr = (tid >> 6) + i * 4, cc = tid & 63;
    t[rr][cc] = s[(size_t)rr * 64 + cc];
  }
  __syncthreads();
#pragma unroll
  for (int i = 0; i < 16; ++i) {
    int rr = (tid >> 6) + i * 4, cc = tid & 63;
    d[(size_t)rr * Ec + cc] = f2bf(t[cc][rr]);
  }
}

// ------- MFMA bf16 GEMM, dbuf + counted-vmcnt (T3+T4) + T2 swizzle ----------
// C[M,N] = A[M,K] * Bt[N,K]^T
// MODE: 0 bf16 out; 1 bf16 out+bias+relu; 2 fp32 C+=acc+bias; 3 fp32 out+bias.
// BSRC: 0 Bt bf16 [N][K]; 1 B fp32 [K][N] (BM=BN=128 only).
// T2: GLDS dest linear, GLOBAL source col pre-swizzled (col8 ^= row&7); reads
// use byte ^= (row&7)<<4 -> conflict-free (verified: SQ_LDS_BANK_CONFLICT=0).
// GX: >1 -> grid=(GX, N/BN, M/BM/GX), bm-fastest (B dedup for logits).
#define GLDS16(g, l)                                              \
  __builtin_amdgcn_global_load_lds(                               \
      (const __attribute__((address_space(1))) void*)(g),         \
      (__attribute__((address_space(3))) void*)(l), 16, 0, 0)

template <int MODE, int BSRC, int BM, int BN, int GX>
__global__ __launch_bounds__(256) void mgemm_k(
    const unsigned short* __restrict__ A, const void* __restrict__ Bv,
    const float* __restrict__ bias, void* __restrict__ Cv,
    int M, int N, int K) {
  constexpr int MI = BM / 32, NF = BN / 32;   // m/n frags per wave
  constexpr int TL = BM / 32 + BN / 32;       // GLDS loads per thread per stage
  __shared__ unsigned short AsU[2][BM * 64];
  __shared__ unsigned short BsU[2][BN * 64];
  const int tid = threadIdx.x, lane = tid & 63, wave = tid >> 6;
  int bm, bn;
  if constexpr (GX == 1) {
    bm = blockIdx.y * BM;
    bn = blockIdx.x * BN;
  } else {
    bm = (blockIdx.z * GX + blockIdx.x) * BM;
    bn = blockIdx.y * BN;
  }
  const int wm = (wave >> 1) * (BM / 2), wn = (wave & 1) * (BN / 2);
  const int fr = lane & 15, fq = lane >> 4;
  const int lr8 = lane >> 3, lc8 = (lane & 7) * 8;
  const int sc8 = ((lane & 7) ^ (lr8 & 7)) * 8;  // T2 pre-swizzled source col
  f32x4 acc[MI][NF];
#pragma unroll
  for (int i = 0; i < MI; ++i)
#pragma unroll
    for (int j = 0; j < NF; ++j) acc[i][j] = (f32x4){0.f, 0.f, 0.f, 0.f};

  auto stage = [&](int k0, int pb) {
    {  // A: source col pre-swizzled; LDS dest linear (row&7 == lr8 for all it)
      const unsigned short* g =
          A + (size_t)(bm + wave * (BM / 4) + lr8) * K + k0 + sc8;
      unsigned short* l = &AsU[pb][(wave * (BM / 4) + lr8) * 64 + lc8];
#pragma unroll
      for (int it = 0; it < BM / 32; ++it)
        GLDS16(g + (size_t)(it * 8) * K, l + it * 8 * 64);
    }
    if constexpr (BSRC == 0) {
      const unsigned short* Bt = (const unsigned short*)Bv;
      const unsigned short* g =
          Bt + (size_t)(bn + wave * (BN / 4) + lr8) * K + k0 + sc8;
      unsigned short* l = &BsU[pb][(wave * (BN / 4) + lr8) * 64 + lc8];
#pragma unroll
      for (int it = 0; it < BN / 32; ++it)
        GLDS16(g + (size_t)(it * 8) * K, l + it * 8 * 64);
    } else {
      const float* Bf = (const float*)Bv;
#pragma unroll
      for (int i = 0; i < 8; ++i) {
        int f4 = i * 256 + tid;
        int kk = f4 >> 5, c4 = (f4 & 31) * 4;
        float4 v = *(const float4*)(Bf + (size_t)(k0 + kk) * N + bn + c4);
        BsU[pb][(c4 + 0) * 64 + kk] = f2bf(v.x);
        BsU[pb][(c4 + 1) * 64 + kk] = f2bf(v.y);
        BsU[pb][(c4 + 2) * 64 + kk] = f2bf(v.z);
        BsU[pb][(c4 + 3) * 64 + kk] = f2bf(v.w);
      }
    }
  };

  auto compute = [&](int pb) {
#pragma unroll
    for (int kk = 0; kk < 2; ++kk) {
      bf16x8 af[MI], bfr[NF];
#pragma unroll
      for (int i = 0; i < MI; ++i) {
        int row = wm + i * 16 + fr;
        af[i] = *(const bf16x8*)((char*)AsU[pb] + row * 128 +
                                 ((kk * 64 + fq * 16) ^ ((row & 7) << 4)));
      }
#pragma unroll
      for (int j = 0; j < NF; ++j) {
        int row = wn + j * 16 + fr;
        if constexpr (BSRC == 0)
          bfr[j] = *(const bf16x8*)((char*)BsU[pb] + row * 128 +
                                    ((kk * 64 + fq * 16) ^ ((row & 7) << 4)));
        else
          bfr[j] = *(const bf16x8*)&BsU[pb][row * 64 + kk * 32 + fq * 8];
      }
#pragma unroll
      for (int i = 0; i < MI; ++i)
#pragma unroll
        for (int j = 0; j < NF; ++j)
          acc[i][j] = __builtin_amdgcn_mfma_f32_16x16x32_bf16(af[i], bfr[j],
                                                              acc[i][j], 0, 0, 0);
    }
  };

  const int nk = K >> 6;
  if constexpr (BSRC == 0) {
    // T3+T4: tile t+1's GLDS loads stay in flight across both barriers.
    stage(0, 0);
    for (int t = 0; t < nk; ++t) {
      const int pb = t & 1;
      if (t + 1 < nk) {
        stage((t + 1) << 6, pb ^ 1);
        if constexpr (TL == 8)      asm volatile("s_waitcnt vmcnt(8)" ::: "memory");
        else if constexpr (TL == 6) asm volatile("s_waitcnt vmcnt(6)" ::: "memory");
        else                        asm volatile("s_waitcnt vmcnt(4)" ::: "memory");
      } else {
        asm volatile("s_waitcnt vmcnt(0)" ::: "memory");
      }
      raw_barrier();        // all waves' tile-t data in LDS
      compute(pb);
      raw_barrier();        // all waves done reading buf[pb]
    }
  } else {
    stage(0, 0);
    __syncthreads();
    for (int t = 0; t < nk; ++t) {
      const int pb = t & 1;
      if (t + 1 < nk) stage((t + 1) << 6, pb ^ 1);
      compute(pb);
      __syncthreads();
    }
  }
#pragma unroll
  for (int i = 0; i < MI; ++i) {
    int row0 = bm + wm + i * 16 + fq * 4;
#pragma unroll
    for (int j = 0; j < NF; ++j) {
      int col = bn + wn + j * 16 + fr;
      float bval = 0.f;
      if constexpr (MODE != 0) bval = bias[col];
#pragma unroll
      for (int r = 0; r < 4; ++r) {
        size_t idx = (size_t)(row0 + r) * N + col;
        float v = acc[i][j][r];
        if constexpr (MODE == 0) {
          ((unsigned short*)Cv)[idx] = f2bf(v);
        } else if constexpr (MODE == 1) {
          ((unsigned short*)Cv)[idx] = f2bf(fmaxf(v + bval, 0.f));
        } else if constexpr (MODE == 2) {
          float* C = (float*)Cv;
          C[idx] = C[idx] + v + bval;
        } else {
          ((float*)Cv)[idx] = v + bval;
        }
      }
    }
  }
}

// ------------- MFMA flash attention, QBLK=64*MI2, K/V double-buffered --------
// MI2=1: 4 waves x 16 q-rows, grid (16,48)=768 blocks -> 3 blocks/CU (latency
// hiding via residency). MI2=2: original 128-row blocks. ONE barrier per tile.
// Ones-column denominator in o[mi][4]. exp2 domain. T13 per-lane defer check.
template <int MI2>
__global__ __launch_bounds__(256) void fattn2_k(const unsigned short* __restrict__ qkv,
                                                unsigned short* __restrict__ att) {
  __shared__ unsigned short Ks[2][64 * 64];
  __shared__ unsigned short Vt[2][80 * 64];
  __shared__ unsigned short Pb[4][16 * 72];
  const int bh = blockIdx.y;
  const int b = bh / Hc, h = bh % Hc;
  const int qb = gridDim.x - 1 - blockIdx.x;   // heavy blocks dispatched first
  const int q0 = qb * (64 * MI2);
  const int tid = threadIdx.x, lane = tid & 63, w = tid >> 6;
  const int fr = lane & 15, fq = lane >> 4;
  const size_t base = (size_t)b * Tc * QKVN + h * 64;
  const int r0 = tid >> 3, c0 = (tid & 7) * 8;          // K staging map
  const int s2 = (tid & 31) * 2, c0v = (tid >> 5) * 8;  // V staging map
  const float SC = 0.125f * 1.44269504f;                // scale * log2(e)

  bf16x8 aq[MI2][2];
#pragma unroll
  for (int mi = 0; mi < MI2; ++mi) {
    const unsigned short* qp =
        qkv + base + (size_t)(q0 + w * 16 * MI2 + mi * 16 + fr) * QKVN + fq * 8;
    aq[mi][0] = *(const bf16x8*)qp;
    aq[mi][1] = *(const bf16x8*)(qp + 32);
  }
  f32x4 o[MI2][5];
  float m_run[MI2][4];
#pragma unroll
  for (int mi = 0; mi < MI2; ++mi)
#pragma unroll
    for (int n = 0; n < 5; ++n) o[mi][n] = (f32x4){0.f, 0.f, 0.f, 0.f};
#pragma unroll
  for (int mi = 0; mi < MI2; ++mi)
#pragma unroll
    for (int r = 0; r < 4; ++r) m_run[mi][r] = -INFINITY;

  {  // init Vt rows 64..79 for BOTH buffers (constant rows)
#pragma unroll
    for (int bx = 0; bx < 2; ++bx) {
      unsigned* vt32 = (unsigned*)(Vt[bx] + 64 * 64);
      vt32[tid] = (tid < 32) ? 0x3F803F80u : 0u;   // row 64 = ones
      vt32[tid + 256] = 0u;                        // rows 72..79
    }
  }

  const int nt = MI2 * (qb + 1);
  uint4 pk0, pk1, pv0, pv1;
  auto loadt = [&](int s0) {
    const unsigned short* kg = qkv + base + Ec + (size_t)(s0 + r0) * QKVN + c0;
    pk0 = *(const uint4*)kg;
    pk1 = *(const uint4*)(kg + (size_t)32 * QKVN);
    const unsigned short* vg =
        qkv + base + 2 * Ec + (size_t)(s0 + s2) * QKVN + c0v;
    pv0 = *(const uint4*)vg;
    pv1 = *(const uint4*)(vg + QKVN);
  };
  auto writet = [&](int bx) {
    *(uint4*)((char*)Ks[bx] + (r0 * 128 + ((c0 * 2) ^ ((r0 & 7) << 4)))) = pk0;
    const int r1 = r0 + 32;
    *(uint4*)((char*)Ks[bx] + (r1 * 128 + ((c0 * 2) ^ ((r1 & 7) << 4)))) = pk1;
    const unsigned short* p0 = (const unsigned short*)&pv0;
    const unsigned short* p1 = (const unsigned short*)&pv1;
#pragma unroll
    for (int j = 0; j < 8; ++j) {
      int hs = c0v + j;
      unsigned pk = (unsigned)p0[j] | ((unsigned)p1[j] << 16);
      *(unsigned*)((char*)Vt[bx] + (hs * 128 + ((s2 * 2) ^ ((hs & 7) << 4)))) = pk;
    }
  };

  loadt(0);
  writet(0);
  __syncthreads();

  for (int it = 0; it < nt; ++it) {
    const int s0 = it * 64;
    const int pb = it & 1;
    if (it + 1 < nt) loadt(s0 + 64);   // T14: issue next-tile loads early

    f32x4 s[MI2][4];
#pragma unroll
    for (int mi = 0; mi < MI2; ++mi)
#pragma unroll
      for (int n = 0; n < 4; ++n) s[mi][n] = (f32x4){0.f, 0.f, 0.f, 0.f};
    __builtin_amdgcn_s_setprio(1);
#pragma unroll
    for (int ss = 0; ss < 2; ++ss)
#pragma unroll
      for (int n = 0; n < 4; ++n) {
        int row = n * 16 + fr;
        bf16x8 kb = *(const bf16x8*)(
            (char*)Ks[pb] + (row * 128 + ((ss * 64 + fq * 16) ^ ((row & 7) << 4))));
#pragma unroll
        for (int mi = 0; mi < MI2; ++mi)
          s[mi][n] = __builtin_amdgcn_mfma_f32_16x16x32_bf16(aq[mi][ss], kb,
                                                             s[mi][n], 0, 0, 0);
      }
    __builtin_amdgcn_s_setprio(0);

#pragma unroll
    for (int mi = 0; mi < MI2; ++mi) {
      const int qlo = q0 + w * 16 * MI2 + mi * 16;
      const bool need_mask = (s0 + 63 > qlo);
#pragma unroll
      for (int n = 0; n < 4; ++n) {
        int scol = s0 + n * 16 + fr;
#pragma unroll
        for (int r = 0; r < 4; ++r) {
          float v = s[mi][n][r] * SC;
          if (need_mask && scol > qlo + fq * 4 + r) v = -INFINITY;
          s[mi][n][r] = v;
        }
      }
      // per-lane defer check: skip cross-lane reduce when bound holds
      bool ok = true;
#pragma unroll
      for (int n = 0; n < 4; ++n)
#pragma unroll
        for (int r = 0; r < 4; ++r)
          ok &= (s[mi][n][r] <= m_run[mi][r] + 8.f);
      if (!__all(ok)) {   // rare: full reduce + rescale
        float mt[4];
#pragma unroll
        for (int r = 0; r < 4; ++r)
          mt[r] = fmaxf(fmaxf(s[mi][0][r], s[mi][1][r]),
                        fmaxf(s[mi][2][r], s[mi][3][r]));
#pragma unroll
        for (int off = 1; off <= 8; off <<= 1)
#pragma unroll
          for (int r = 0; r < 4; ++r)
            mt[r] = fmaxf(mt[r], __shfl_xor(mt[r], off, 64));
        float alpha[4];
#pragma unroll
        for (int r = 0; r < 4; ++r) {
          float mn = fmaxf(m_run[mi][r], mt[r]);
          alpha[r] = exp2f(m_run[mi][r] - mn);
          m_run[mi][r] = mn;
        }
#pragma unroll
        for (int n = 0; n < 5; ++n)       // includes denominator column
#pragma unroll
          for (int r = 0; r < 4; ++r) o[mi][n][r] *= alpha[r];
      }
#pragma unroll
      for (int n = 0; n < 4; ++n)
#pragma unroll
        for (int r = 0; r < 4; ++r)
          Pb[w][(fq * 4 + r) * 72 + n * 16 + fr] =
              f2bf(exp2f(s[mi][n][r] - m_run[mi][r]));
      __builtin_amdgcn_s_setprio(1);
#pragma unroll
      for (int ss = 0; ss < 2; ++ss) {
        bf16x8 pa = *(const bf16x8*)&Pb[w][fr * 72 + ss * 32 + fq * 8];
#pragma unroll
        for (int n = 0; n < 5; ++n) {     // n=4: ones column -> row-sum (l)
          int row = n * 16 + fr;
          bf16x8 vb = *(const bf16x8*)(
              (char*)Vt[pb] + (row * 128 + ((ss * 64 + fq * 16) ^ ((row & 7) << 4))));
          o[mi][n] = __builtin_amdgcn_mfma_f32_16x16x32_bf16(pa, vb, o[mi][n],
                                                             0, 0, 0);
        }
      }
      __builtin_amdgcn_s_setprio(0);
    }

    if (it + 1 < nt) writet(pb ^ 1);   // fill other buffer
    __syncthreads();                   // ONE barrier per tile
  }
  // epilogue: l for row (fq,r) lives at lane fq*16 (col 64); broadcast per group
#pragma unroll
  for (int mi = 0; mi < MI2; ++mi)
#pragma unroll
    for (int r = 0; r < 4; ++r) {
      const float l = __shfl(o[mi][4][r], lane & 48, 64);
      const float inv = 1.0f / l;
      const int qrow = q0 + w * 16 * MI2 + mi * 16 + fq * 4 + r;
      unsigned short* orow = att + ((size_t)(b * Tc + qrow)) * Ec + h * 64;
#pragma unroll
      for (int n = 0; n < 4; ++n) orow[n * 16 + fr] = f2bf(o[mi][n][r] * inv);
    }
}

// ---------------- online-softmax cross-entropy (nontemporal reads) ----------
__global__ __launch_bounds__(256) void loss_k(const float* __restrict__ logits,
                                              const int* __restrict__ targets,
                                              float* __restrict__ rowloss) {
  __shared__ float redm[4], reds[4];
  const int row = blockIdx.x, tid = threadIdx.x;
  const f32x4* lr4 = (const f32x4*)(logits + (size_t)row * Vc);
  float m = -INFINITY, s = 0.f;
  for (int j = tid; j < Vc / 4; j += 256) {
    f32x4 v = __builtin_nontemporal_load(lr4 + j);
    float m0 = fmaxf(fmaxf(v[0], v[1]), fmaxf(v[2], v[3]));
    float nm = fmaxf(m, m0);
    s = s * __expf(m - nm) + __expf(v[0] - nm) + __expf(v[1] - nm) +
        __expf(v[2] - nm) + __expf(v[3] - nm);
    m = nm;
  }
#pragma unroll
  for (int off = 32; off; off >>= 1) {
    float om = __shfl_xor(m, off, 64), os = __shfl_xor(s, off, 64);
    float nm = fmaxf(m, om);
    s = s * __expf(m - nm) + os * __expf(om - nm);
    m = nm;
  }
  if ((tid & 63) == 0) { redm[tid >> 6] = m; reds[tid >> 6] = s; }
  __syncthreads();
  if (tid == 0) {
    float M2 = redm[0], S2 = reds[0];
#pragma unroll
    for (int w = 1; w < 4; ++w) {
      float om = redm[w], os = reds[w];
      float nm = fmaxf(M2, om);
      S2 = S2 * __expf(M2 - nm) + os * __expf(om - nm);
      M2 = nm;
    }
    float lt = logits[(size_t)row * Vc + targets[row]];
    rowloss[row] = -(lt - M2 - logf(S2));
  }
}

__global__ __launch_bounds__(1024) void lossred_k(const float* __restrict__ rowloss,
                                                  float* __restrict__ outp) {
  __shared__ float red[16];
  float s = 0.f;
  for (int i = threadIdx.x; i < Mc; i += 1024) s += rowloss[i];
  s = wave_sum(s);
  if ((threadIdx.x & 63) == 0) red[threadIdx.x >> 6] = s;
  __syncthreads();
  if (threadIdx.x == 0) {
    float tot = 0.f;
#pragma unroll
    for (int i = 0; i < 16; ++i) tot += red[i];
    outp[0] = tot * (1.0f / (float)Mc);
  }
}

}  // namespace

extern "C" void kernel_launch(void* const* d_in, const int* in_sizes, int n_in,
                              void* d_out, int out_size, void* d_ws, size_t ws_size,
                              hipStream_t stream) {
  const int*   tokens  = (const int*)d_in[0];
  const int*   targets = (const int*)d_in[1];
  const float* tok_emb = (const float*)d_in[2];
  const float* pet     = (const float*)d_in[3];
  const float* wq      = (const float*)d_in[4];
  const float* wk      = (const float*)d_in[5];
  const float* wv      = (const float*)d_in[6];
  const float* w_proj  = (const float*)d_in[7];
  const float* b_proj  = (const float*)d_in[8];
  const float* ln1_g   = (const float*)d_in[9];
  const float* ln1_b   = (const float*)d_in[10];
  const float* ln2_g   = (const float*)d_in[11];
  const float* ln2_b   = (const float*)d_in[12];
  const float* w_ff1   = (const float*)d_in[13];
  const float* b_ff1   = (const float*)d_in[14];
  const float* w_ff2   = (const float*)d_in[15];
  const float* b_ff2   = (const float*)d_in[16];
  const float* lnf_g   = (const float*)d_in[17];
  const float* lnf_b   = (const float*)d_in[18];
  const float* w_out   = (const float*)d_in[19];
  const float* b_out   = (const float*)d_in[20];

  float* out = (float*)d_out;
  char* ob = (char*)d_out;
  // scratch inside dead logits region of d_out (write-before-read per call)
  unsigned short* qkvA  = (unsigned short*)(ob + 0);          // [M][2304] bf16
  unsigned short* attA  = (unsigned short*)(ob + 18874368);   // [M][768]  bf16
  unsigned short* ffhA  = (unsigned short*)(ob + 25165824);   // [M][3072] bf16
  unsigned short* qkvT  = (unsigned short*)(ob + 50331648);   // [L][2304][768]
  unsigned short* projT = (unsigned short*)(ob + 71565312);   // [L][768][768]
  unsigned short* ff1T  = (unsigned short*)(ob + 78643200);   // [L][3072][768]
  unsigned short* ff2T  = (unsigned short*)(ob + 106954752);  // [L][768][3072]
  char* wb = (char*)d_ws;
  float* x = (float*)wb;                                       // 12,582,912 B
  unsigned short* hbuf = (unsigned short*)(wb + 12582912);     //  6,291,456 B
  float* rowloss = (float*)(wb + 18874368);                    //     16,384 B
  unsigned short* woutT = (unsigned short*)(wb + 18890752);    // 49,152,000 B
  const bool wfit = ws_size >= (size_t)18890752 + 49152000;

  qcvt_k<<<dim3(12, 3 * Lc * Hc), 256, 0, stream>>>(wq, wk, wv, qkvT);
  tcvt_k<<<dim3(12, 12, 6), 256, 0, stream>>>(w_proj, projT, 768, 768,
                                              (size_t)589824, (size_t)589824);
  tcvt_k<<<dim3(48, 12, 6), 256, 0, stream>>>(w_ff1, ff1T, 768, 3072,
                                              (size_t)768 * 3072, (size_t)768 * 3072);
  tcvt_k<<<dim3(12, 48, 6), 256, 0, stream>>>(w_ff2, ff2T, 3072, 768,
                                              (size_t)768 * 3072, (size_t)768 * 3072);
  if (wfit)
    tcvt_k<<<dim3(500, 12, 1), 256, 0, stream>>>(w_out, woutT, 768, 32000, 0, 0);

  embed_k<<<(Mc * Ec) / 256, 256, 0, stream>>>(tokens, tok_emb, pet, x);

  for (int l = 0; l < Lc; ++l) {
    ln_k<<<Mc, 256, 0, stream>>>(x, ln1_g + (size_t)l * Ec, ln1_b + (size_t)l * Ec, hbuf);
    // qkv: 128x64 tile, grid 1152
    mgemm_k<0, 0, 128, 64, 1><<<dim3(36, 32), 256, 0, stream>>>(
        hbuf, qkvT + (size_t)l * QKVN * Ec, nullptr, qkvA, Mc, QKVN, Ec);
    // attention: QBLK=64, 768 blocks -> 3 blocks/CU residency
    fattn2_k<1><<<dim3(Tc / 64, Bc * Hc), 256, 0, stream>>>(qkvA, attA);
    // proj: 64x64 tile, grid 768 = 3/CU exact
    mgemm_k<2, 0, 64, 64, 1><<<dim3(12, 64), 256, 0, stream>>>(
        attA, projT + (size_t)l * Ec * Ec, b_proj + (size_t)l * Ec, x, Mc, Ec, Ec);
    ln_k<<<Mc, 256, 0, stream>>>(x, ln2_g + (size_t)l * Ec, ln2_b + (size_t)l * Ec, hbuf);
    // ff1: 128x64 tile, grid 1536 = 6/CU exact
    mgemm_k<1, 0, 128, 64, 1><<<dim3(48, 32), 256, 0, stream>>>(
        hbuf, ff1T + (size_t)l * Ec * FFc, b_ff1 + (size_t)l * FFc, ffhA, Mc, FFc, Ec);
    // ff2: 64x64 tile, grid 768 = 3/CU exact
    mgemm_k<2, 0, 64, 64, 1><<<dim3(12, 64), 256, 0, stream>>>(
        ffhA, ff2T + (size_t)l * Ec * FFc, b_ff2 + (size_t)l * Ec, x, Mc, Ec, FFc);
  }
  ln_k<<<Mc, 256, 0, stream>>>(x, lnf_g, lnf_b, hbuf);
  // logits GEMM: round-15 proven config (bm-fastest dedup, T2, PIPE=2, 128x128)
  if (wfit)
    mgemm_k<3, 0, 128, 128, 32><<<dim3(32, 250, 1), 256, 0, stream>>>(
        hbuf, woutT, b_out, out, Mc, Vc, Ec);
  else
    mgemm_k<3, 1, 128, 128, 1><<<dim3(250, 32), 256, 0, stream>>>(
        hbuf, w_out, b_out, out, Mc, Vc, Ec);
  loss_k<<<Mc, 256, 0, stream>>>(out, targets, rowloss);
  lossred_k<<<1, 1024, 0, stream>>>(rowloss, out + (size_t)Mc * Vc);
}

// Round 18
// 1525.826 us; speedup vs baseline: 1.1226x; 1.0415x over previous
//
#include <hip/hip_runtime.h>
#include <math.h>

namespace {

constexpr int Bc = 4, Tc = 1024, Ec = 768, Hc = 12, Lc = 6;
constexpr int Vc = 32000, FFc = 3072, Mc = Bc * Tc;   // M = 4096
constexpr int QKVN = 3 * Ec;                          // 2304

typedef __bf16 bf16x8 __attribute__((ext_vector_type(8)));
typedef float f32x4 __attribute__((ext_vector_type(4)));

__device__ __forceinline__ unsigned short f2bf(float f) {
  unsigned u = __builtin_bit_cast(unsigned, f);
  u += 0x7FFFu + ((u >> 16) & 1u);
  return (unsigned short)(u >> 16);
}

__device__ __forceinline__ float wave_sum(float v) {
#pragma unroll
  for (int off = 32; off > 0; off >>= 1) v += __shfl_xor(v, off, 64);
  return v;
}
__device__ __forceinline__ float block_sum256(float v, volatile float* red) {
  v = wave_sum(v);
  __syncthreads();
  if ((threadIdx.x & 63) == 0) red[threadIdx.x >> 6] = v;
  __syncthreads();
  return red[0] + red[1] + red[2] + red[3];
}
// raw workgroup barrier with compiler memory fences (no vmcnt(0) drain)
__device__ __forceinline__ void raw_barrier() {
  asm volatile("" ::: "memory");
  __builtin_amdgcn_s_barrier();
  asm volatile("" ::: "memory");
}

// ---------------- embedding ----------------
__global__ __launch_bounds__(256) void embed_k(const int* __restrict__ tokens,
                                               const float* __restrict__ emb,
                                               const float* __restrict__ pet,
                                               float* __restrict__ x) {
  int i = blockIdx.x * 256 + threadIdx.x;
  int m = i / Ec, e = i - m * Ec;
  int tok = tokens[m];
  x[i] = emb[(size_t)tok * Ec + e] + pet[(size_t)(m & (Tc - 1)) * Ec + e];
}

// ---------------- layernorm: fp32 in -> bf16 out ----------------
__global__ __launch_bounds__(256) void ln_k(const float* __restrict__ in,
                                            const float* __restrict__ g,
                                            const float* __restrict__ bb,
                                            unsigned short* __restrict__ outp) {
  __shared__ float red[4];
  int row = blockIdx.x, tid = threadIdx.x;
  const float* xr = in + (size_t)row * Ec;
  float v0 = xr[tid], v1 = xr[tid + 256], v2 = xr[tid + 512];
  float mean = block_sum256(v0 + v1 + v2, red) * (1.0f / 768.0f);
  float d0 = v0 - mean, d1 = v1 - mean, d2 = v2 - mean;
  float var = block_sum256(d0 * d0 + d1 * d1 + d2 * d2, red) * (1.0f / 768.0f);
  float rs = rsqrtf(var + 1e-5f);
  unsigned short* orow = outp + (size_t)row * Ec;
  orow[tid]       = f2bf(d0 * rs * g[tid]       + bb[tid]);
  orow[tid + 256] = f2bf(d1 * rs * g[tid + 256] + bb[tid + 256]);
  orow[tid + 512] = f2bf(d2 * rs * g[tid + 512] + bb[tid + 512]);
}

// ------- weight convert: [K][N] fp32 -> [N][K] bf16, batched -------
__global__ __launch_bounds__(256) void tcvt_k(const float* __restrict__ src,
                                              unsigned short* __restrict__ dst,
                                              int K, int N,
                                              size_t srcBatch, size_t dstBatch) {
  __shared__ float t[64][65];
  const float* s = src + blockIdx.z * srcBatch;
  unsigned short* d = dst + blockIdx.z * dstBatch;
  int k0 = blockIdx.y * 64, n0 = blockIdx.x * 64;
  int tid = threadIdx.x;
#pragma unroll
  for (int i = 0; i < 16; ++i) {
    int rr = (tid >> 6) + i * 4, cc = tid & 63;
    t[rr][cc] = s[(size_t)(k0 + rr) * N + n0 + cc];
  }
  __syncthreads();
#pragma unroll
  for (int i = 0; i < 16; ++i) {
    int rr = (tid >> 6) + i * 4, cc = tid & 63;
    d[(size_t)(n0 + rr) * K + k0 + cc] = f2bf(t[cc][rr]);
  }
}

// ------- wq/wk/wv [L][H][E][HS] fp32 -> fused qkvT [L][2304][768] bf16 -------
__global__ __launch_bounds__(256) void qcvt_k(const float* __restrict__ wq,
                                              const float* __restrict__ wk,
                                              const float* __restrict__ wv,
                                              unsigned short* __restrict__ dst) {
  __shared__ float t[64][65];
  const int which = blockIdx.y / (Lc * Hc);
  const int z = blockIdx.y % (Lc * Hc), l = z / Hc, h = z % Hc;
  const float* src = which == 0 ? wq : (which == 1 ? wk : wv);
  const int k0 = blockIdx.x * 64;
  const int tid = threadIdx.x;
  const float* s = src + ((size_t)z * Ec + k0) * 64;
  unsigned short* d =
      dst + (size_t)l * QKVN * Ec + ((size_t)which * Ec + h * 64) * Ec + k0;
#pragma unroll
  for (int i = 0; i < 16; ++i) {
    int rr = (tid >> 6) + i * 4, cc = tid & 63;
    t[rr][cc] = s[(size_t)rr * 64 + cc];
  }
  __syncthreads();
#pragma unroll
  for (int i = 0; i < 16; ++i) {
    int rr = (tid >> 6) + i * 4, cc = tid & 63;
    d[(size_t)rr * Ec + cc] = f2bf(t[cc][rr]);
  }
}

// ------- MFMA bf16 GEMM, dbuf + counted-vmcnt (T3+T4) + T2 swizzle ----------
// C[M,N] = A[M,K] * Bt[N,K]^T
// MODE: 0 bf16 out; 1 bf16 out+bias+relu; 2 fp32 C+=acc+bias; 3 fp32 out+bias;
//       4 fp32 out+bias + per-row SUMEXP partial -> pbuf[row][bn/128]
//       (no max: |logits| ~ 3 << 88, fp32 sum-exp is exact enough).
// BSRC: 0 Bt bf16 [N][K]; 1 B fp32 [K][N] (BM=BN=128 only).
// T2: GLDS dest linear, GLOBAL source col pre-swizzled (col8 ^= row&7); reads
// use byte ^= (row&7)<<4 -> conflict-free (verified: SQ_LDS_BANK_CONFLICT=0).
// GX: >1 -> grid=(GX, N/BN, M/BM/GX), bm-fastest (B dedup for logits).
#define GLDS16(g, l)                                              \
  __builtin_amdgcn_global_load_lds(                               \
      (const __attribute__((address_space(1))) void*)(g),         \
      (__attribute__((address_space(3))) void*)(l), 16, 0, 0)

template <int MODE, int BSRC, int BM, int BN, int GX>
__global__ __launch_bounds__(256) void mgemm_k(
    const unsigned short* __restrict__ A, const void* __restrict__ Bv,
    const float* __restrict__ bias, void* __restrict__ Cv,
    int M, int N, int K, float* __restrict__ pbuf) {
  constexpr int MI = BM / 32, NF = BN / 32;   // m/n frags per wave
  constexpr int TL = BM / 32 + BN / 32;       // GLDS loads per thread per stage
  __shared__ unsigned short AsU[2][BM * 64];
  __shared__ unsigned short BsU[2][BN * 64];
  const int tid = threadIdx.x, lane = tid & 63, wave = tid >> 6;
  int bm, bn;
  if constexpr (GX == 1) {
    bm = blockIdx.y * BM;
    bn = blockIdx.x * BN;
  } else {
    bm = (blockIdx.z * GX + blockIdx.x) * BM;
    bn = blockIdx.y * BN;
  }
  const int wm = (wave >> 1) * (BM / 2), wn = (wave & 1) * (BN / 2);
  const int fr = lane & 15, fq = lane >> 4;
  const int lr8 = lane >> 3, lc8 = (lane & 7) * 8;
  const int sc8 = ((lane & 7) ^ (lr8 & 7)) * 8;  // T2 pre-swizzled source col
  f32x4 acc[MI][NF];
#pragma unroll
  for (int i = 0; i < MI; ++i)
#pragma unroll
    for (int j = 0; j < NF; ++j) acc[i][j] = (f32x4){0.f, 0.f, 0.f, 0.f};

  auto stage = [&](int k0, int pb) {
    {  // A: source col pre-swizzled; LDS dest linear (row&7 == lr8 for all it)
      const unsigned short* g =
          A + (size_t)(bm + wave * (BM / 4) + lr8) * K + k0 + sc8;
      unsigned short* l = &AsU[pb][(wave * (BM / 4) + lr8) * 64 + lc8];
#pragma unroll
      for (int it = 0; it < BM / 32; ++it)
        GLDS16(g + (size_t)(it * 8) * K, l + it * 8 * 64);
    }
    if constexpr (BSRC == 0) {
      const unsigned short* Bt = (const unsigned short*)Bv;
      const unsigned short* g =
          Bt + (size_t)(bn + wave * (BN / 4) + lr8) * K + k0 + sc8;
      unsigned short* l = &BsU[pb][(wave * (BN / 4) + lr8) * 64 + lc8];
#pragma unroll
      for (int it = 0; it < BN / 32; ++it)
        GLDS16(g + (size_t)(it * 8) * K, l + it * 8 * 64);
    } else {
      const float* Bf = (const float*)Bv;
#pragma unroll
      for (int i = 0; i < 8; ++i) {
        int f4 = i * 256 + tid;
        int kk = f4 >> 5, c4 = (f4 & 31) * 4;
        float4 v = *(const float4*)(Bf + (size_t)(k0 + kk) * N + bn + c4);
        BsU[pb][(c4 + 0) * 64 + kk] = f2bf(v.x);
        BsU[pb][(c4 + 1) * 64 + kk] = f2bf(v.y);
        BsU[pb][(c4 + 2) * 64 + kk] = f2bf(v.z);
        BsU[pb][(c4 + 3) * 64 + kk] = f2bf(v.w);
      }
    }
  };

  auto compute = [&](int pb) {
#pragma unroll
    for (int kk = 0; kk < 2; ++kk) {
      bf16x8 af[MI], bfr[NF];
#pragma unroll
      for (int i = 0; i < MI; ++i) {
        int row = wm + i * 16 + fr;
        af[i] = *(const bf16x8*)((char*)AsU[pb] + row * 128 +
                                 ((kk * 64 + fq * 16) ^ ((row & 7) << 4)));
      }
#pragma unroll
      for (int j = 0; j < NF; ++j) {
        int row = wn + j * 16 + fr;
        if constexpr (BSRC == 0)
          bfr[j] = *(const bf16x8*)((char*)BsU[pb] + row * 128 +
                                    ((kk * 64 + fq * 16) ^ ((row & 7) << 4)));
        else
          bfr[j] = *(const bf16x8*)&BsU[pb][row * 64 + kk * 32 + fq * 8];
      }
#pragma unroll
      for (int i = 0; i < MI; ++i)
#pragma unroll
        for (int j = 0; j < NF; ++j)
          acc[i][j] = __builtin_amdgcn_mfma_f32_16x16x32_bf16(af[i], bfr[j],
                                                              acc[i][j], 0, 0, 0);
    }
  };

  const int nk = K >> 6;
  if constexpr (BSRC == 0) {
    // T3+T4: tile t+1's GLDS loads stay in flight across both barriers.
    stage(0, 0);
    for (int t = 0; t < nk; ++t) {
      const int pb = t & 1;
      if (t + 1 < nk) {
        stage((t + 1) << 6, pb ^ 1);
        if constexpr (TL == 8)      asm volatile("s_waitcnt vmcnt(8)" ::: "memory");
        else if constexpr (TL == 6) asm volatile("s_waitcnt vmcnt(6)" ::: "memory");
        else                        asm volatile("s_waitcnt vmcnt(4)" ::: "memory");
      } else {
        asm volatile("s_waitcnt vmcnt(0)" ::: "memory");
      }
      raw_barrier();        // all waves' tile-t data in LDS
      compute(pb);
      raw_barrier();        // all waves done reading buf[pb]
    }
  } else {
    stage(0, 0);
    __syncthreads();
    for (int t = 0; t < nk; ++t) {
      const int pb = t & 1;
      if (t + 1 < nk) stage((t + 1) << 6, pb ^ 1);
      compute(pb);
      __syncthreads();
    }
  }
  if constexpr (MODE == 4) {
    // fp32 out + bias + per-row sum-exp partial (NO max; pure add-reduce).
    // pms reuses AsU[0] (last compute read buffer pb = (nk-1)&1 = 1).
    float* pms = (float*)AsU;   // [BM][2]
    float* C = (float*)Cv;
    float srow[MI][4];
#pragma unroll
    for (int i = 0; i < MI; ++i) {
      int row0 = bm + wm + i * 16 + fq * 4;
#pragma unroll
      for (int r = 0; r < 4; ++r) {
        float s = 0.f;
#pragma unroll
        for (int j = 0; j < NF; ++j) {
          int col = bn + wn + j * 16 + fr;
          float v = acc[i][j][r] + bias[col];
          C[(size_t)(row0 + r) * N + col] = v;
          s += __expf(v);
        }
        srow[i][r] = s;
      }
    }
#pragma unroll
    for (int off = 1; off <= 8; off <<= 1)
#pragma unroll
      for (int i = 0; i < MI; ++i)
#pragma unroll
        for (int r = 0; r < 4; ++r)
          srow[i][r] += __shfl_xor(srow[i][r], off, 64);
    if (fr == 0) {
#pragma unroll
      for (int i = 0; i < MI; ++i)
#pragma unroll
        for (int r = 0; r < 4; ++r)
          pms[(wm + i * 16 + fq * 4 + r) * 2 + (wave & 1)] = srow[i][r];
    }
    __syncthreads();
    if (tid < BM)
      pbuf[(size_t)(bm + tid) * 250 + (bn >> 7)] =
          pms[tid * 2 + 0] + pms[tid * 2 + 1];
    return;
  }
#pragma unroll
  for (int i = 0; i < MI; ++i) {
    int row0 = bm + wm + i * 16 + fq * 4;
#pragma unroll
    for (int j = 0; j < NF; ++j) {
      int col = bn + wn + j * 16 + fr;
      float bval = 0.f;
      if constexpr (MODE != 0) bval = bias[col];
#pragma unroll
      for (int r = 0; r < 4; ++r) {
        size_t idx = (size_t)(row0 + r) * N + col;
        float v = acc[i][j][r];
        if constexpr (MODE == 0) {
          ((unsigned short*)Cv)[idx] = f2bf(v);
        } else if constexpr (MODE == 1) {
          ((unsigned short*)Cv)[idx] = f2bf(fmaxf(v + bval, 0.f));
        } else if constexpr (MODE == 2) {
          float* C = (float*)Cv;
          C[idx] = C[idx] + v + bval;
        } else {
          ((float*)Cv)[idx] = v + bval;
        }
      }
    }
  }
}

// ------------- MFMA flash attention, QBLK=64*MI2, K/V double-buffered --------
// MI2=1: 4 waves x 16 q-rows, grid (16,48)=768 blocks -> 3 blocks/CU. ONE
// barrier per tile. Ones-column denominator in o[mi][4]. exp2 domain. T13
// per-lane defer check.
template <int MI2>
__global__ __launch_bounds__(256) void fattn2_k(const unsigned short* __restrict__ qkv,
                                                unsigned short* __restrict__ att) {
  __shared__ unsigned short Ks[2][64 * 64];
  __shared__ unsigned short Vt[2][80 * 64];
  __shared__ unsigned short Pb[4][16 * 72];
  const int bh = blockIdx.y;
  const int b = bh / Hc, h = bh % Hc;
  const int qb = gridDim.x - 1 - blockIdx.x;   // heavy blocks dispatched first
  const int q0 = qb * (64 * MI2);
  const int tid = threadIdx.x, lane = tid & 63, w = tid >> 6;
  const int fr = lane & 15, fq = lane >> 4;
  const size_t base = (size_t)b * Tc * QKVN + h * 64;
  const int r0 = tid >> 3, c0 = (tid & 7) * 8;          // K staging map
  const int s2 = (tid & 31) * 2, c0v = (tid >> 5) * 8;  // V staging map
  const float SC = 0.125f * 1.44269504f;                // scale * log2(e)

  bf16x8 aq[MI2][2];
#pragma unroll
  for (int mi = 0; mi < MI2; ++mi) {
    const unsigned short* qp =
        qkv + base + (size_t)(q0 + w * 16 * MI2 + mi * 16 + fr) * QKVN + fq * 8;
    aq[mi][0] = *(const bf16x8*)qp;
    aq[mi][1] = *(const bf16x8*)(qp + 32);
  }
  f32x4 o[MI2][5];
  float m_run[MI2][4];
#pragma unroll
  for (int mi = 0; mi < MI2; ++mi)
#pragma unroll
    for (int n = 0; n < 5; ++n) o[mi][n] = (f32x4){0.f, 0.f, 0.f, 0.f};
#pragma unroll
  for (int mi = 0; mi < MI2; ++mi)
#pragma unroll
    for (int r = 0; r < 4; ++r) m_run[mi][r] = -INFINITY;

  {  // init Vt rows 64..79 for BOTH buffers (constant rows)
#pragma unroll
    for (int bx = 0; bx < 2; ++bx) {
      unsigned* vt32 = (unsigned*)(Vt[bx] + 64 * 64);
      vt32[tid] = (tid < 32) ? 0x3F803F80u : 0u;   // row 64 = ones
      vt32[tid + 256] = 0u;                        // rows 72..79
    }
  }

  const int nt = MI2 * (qb + 1);
  uint4 pk0, pk1, pv0, pv1;
  auto loadt = [&](int s0) {
    const unsigned short* kg = qkv + base + Ec + (size_t)(s0 + r0) * QKVN + c0;
    pk0 = *(const uint4*)kg;
    pk1 = *(const uint4*)(kg + (size_t)32 * QKVN);
    const unsigned short* vg =
        qkv + base + 2 * Ec + (size_t)(s0 + s2) * QKVN + c0v;
    pv0 = *(const uint4*)vg;
    pv1 = *(const uint4*)(vg + QKVN);
  };
  auto writet = [&](int bx) {
    *(uint4*)((char*)Ks[bx] + (r0 * 128 + ((c0 * 2) ^ ((r0 & 7) << 4)))) = pk0;
    const int r1 = r0 + 32;
    *(uint4*)((char*)Ks[bx] + (r1 * 128 + ((c0 * 2) ^ ((r1 & 7) << 4)))) = pk1;
    const unsigned short* p0 = (const unsigned short*)&pv0;
    const unsigned short* p1 = (const unsigned short*)&pv1;
#pragma unroll
    for (int j = 0; j < 8; ++j) {
      int hs = c0v + j;
      unsigned pk = (unsigned)p0[j] | ((unsigned)p1[j] << 16);
      *(unsigned*)((char*)Vt[bx] + (hs * 128 + ((s2 * 2) ^ ((hs & 7) << 4)))) = pk;
    }
  };

  loadt(0);
  writet(0);
  __syncthreads();

  for (int it = 0; it < nt; ++it) {
    const int s0 = it * 64;
    const int pb = it & 1;
    if (it + 1 < nt) loadt(s0 + 64);   // T14: issue next-tile loads early

    f32x4 s[MI2][4];
#pragma unroll
    for (int mi = 0; mi < MI2; ++mi)
#pragma unroll
      for (int n = 0; n < 4; ++n) s[mi][n] = (f32x4){0.f, 0.f, 0.f, 0.f};
    __builtin_amdgcn_s_setprio(1);
#pragma unroll
    for (int ss = 0; ss < 2; ++ss)
#pragma unroll
      for (int n = 0; n < 4; ++n) {
        int row = n * 16 + fr;
        bf16x8 kb = *(const bf16x8*)(
            (char*)Ks[pb] + (row * 128 + ((ss * 64 + fq * 16) ^ ((row & 7) << 4))));
#pragma unroll
        for (int mi = 0; mi < MI2; ++mi)
          s[mi][n] = __builtin_amdgcn_mfma_f32_16x16x32_bf16(aq[mi][ss], kb,
                                                             s[mi][n], 0, 0, 0);
      }
    __builtin_amdgcn_s_setprio(0);

#pragma unroll
    for (int mi = 0; mi < MI2; ++mi) {
      const int qlo = q0 + w * 16 * MI2 + mi * 16;
      const bool need_mask = (s0 + 63 > qlo);
#pragma unroll
      for (int n = 0; n < 4; ++n) {
        int scol = s0 + n * 16 + fr;
#pragma unroll
        for (int r = 0; r < 4; ++r) {
          float v = s[mi][n][r] * SC;
          if (need_mask && scol > qlo + fq * 4 + r) v = -INFINITY;
          s[mi][n][r] = v;
        }
      }
      // per-lane defer check: skip cross-lane reduce when bound holds
      bool ok = true;
#pragma unroll
      for (int n = 0; n < 4; ++n)
#pragma unroll
        for (int r = 0; r < 4; ++r)
          ok &= (s[mi][n][r] <= m_run[mi][r] + 8.f);
      if (!__all(ok)) {   // rare: full reduce + rescale
        float mt[4];
#pragma unroll
        for (int r = 0; r < 4; ++r)
          mt[r] = fmaxf(fmaxf(s[mi][0][r], s[mi][1][r]),
                        fmaxf(s[mi][2][r], s[mi][3][r]));
#pragma unroll
        for (int off = 1; off <= 8; off <<= 1)
#pragma unroll
          for (int r = 0; r < 4; ++r)
            mt[r] = fmaxf(mt[r], __shfl_xor(mt[r], off, 64));
        float alpha[4];
#pragma unroll
        for (int r = 0; r < 4; ++r) {
          float mn = fmaxf(m_run[mi][r], mt[r]);
          alpha[r] = exp2f(m_run[mi][r] - mn);
          m_run[mi][r] = mn;
        }
#pragma unroll
        for (int n = 0; n < 5; ++n)       // includes denominator column
#pragma unroll
          for (int r = 0; r < 4; ++r) o[mi][n][r] *= alpha[r];
      }
#pragma unroll
      for (int n = 0; n < 4; ++n)
#pragma unroll
        for (int r = 0; r < 4; ++r)
          Pb[w][(fq * 4 + r) * 72 + n * 16 + fr] =
              f2bf(exp2f(s[mi][n][r] - m_run[mi][r]));
      __builtin_amdgcn_s_setprio(1);
#pragma unroll
      for (int ss = 0; ss < 2; ++ss) {
        bf16x8 pa = *(const bf16x8*)&Pb[w][fr * 72 + ss * 32 + fq * 8];
#pragma unroll
        for (int n = 0; n < 5; ++n) {     // n=4: ones column -> row-sum (l)
          int row = n * 16 + fr;
          bf16x8 vb = *(const bf16x8*)(
              (char*)Vt[pb] + (row * 128 + ((ss * 64 + fq * 16) ^ ((row & 7) << 4))));
          o[mi][n] = __builtin_amdgcn_mfma_f32_16x16x32_bf16(pa, vb, o[mi][n],
                                                             0, 0, 0);
        }
      }
      __builtin_amdgcn_s_setprio(0);
    }

    if (it + 1 < nt) writet(pb ^ 1);   // fill other buffer
    __syncthreads();                   // ONE barrier per tile
  }
  // epilogue: l for row (fq,r) lives at lane fq*16 (col 64); broadcast per group
#pragma unroll
  for (int mi = 0; mi < MI2; ++mi)
#pragma unroll
    for (int r = 0; r < 4; ++r) {
      const float l = __shfl(o[mi][4][r], lane & 48, 64);
      const float inv = 1.0f / l;
      const int qrow = q0 + w * 16 * MI2 + mi * 16 + fq * 4 + r;
      unsigned short* orow = att + ((size_t)(b * Tc + qrow)) * Ec + h * 64;
#pragma unroll
      for (int n = 0; n < 4; ++n) orow[n * 16 + fr] = f2bf(o[mi][n][r] * inv);
    }
}

// ---------------- loss from fused sum-exp partials ----------------
__global__ __launch_bounds__(256) void lossfin_k(const float* __restrict__ pbuf,
                                                 const float* __restrict__ logits,
                                                 const int* __restrict__ targets,
                                                 float* __restrict__ rowloss) {
  const int row = blockIdx.x * 4 + (threadIdx.x >> 6);
  const int lane = threadIdx.x & 63;
  const float* p = pbuf + (size_t)row * 250;
  float s = 0.f;
  for (int j = lane; j < 250; j += 64) s += p[j];
  s = wave_sum(s);
  if (lane == 0) {
    float lt = logits[(size_t)row * Vc + targets[row]];
    rowloss[row] = logf(s) - lt;
  }
}

// ---------------- fallback: online-softmax cross-entropy --------------------
__global__ __launch_bounds__(256) void loss_k(const float* __restrict__ logits,
                                              const int* __restrict__ targets,
                                              float* __restrict__ rowloss) {
  __shared__ float redm[4], reds[4];
  const int row = blockIdx.x, tid = threadIdx.x;
  const f32x4* lr4 = (const f32x4*)(logits + (size_t)row * Vc);
  float m = -INFINITY, s = 0.f;
  for (int j = tid; j < Vc / 4; j += 256) {
    f32x4 v = __builtin_nontemporal_load(lr4 + j);
    float m0 = fmaxf(fmaxf(v[0], v[1]), fmaxf(v[2], v[3]));
    float nm = fmaxf(m, m0);
    s = s * __expf(m - nm) + __expf(v[0] - nm) + __expf(v[1] - nm) +
        __expf(v[2] - nm) + __expf(v[3] - nm);
    m = nm;
  }
#pragma unroll
  for (int off = 32; off; off >>= 1) {
    float om = __shfl_xor(m, off, 64), os = __shfl_xor(s, off, 64);
    float nm = fmaxf(m, om);
    s = s * __expf(m - nm) + os * __expf(om - nm);
    m = nm;
  }
  if ((tid & 63) == 0) { redm[tid >> 6] = m; reds[tid >> 6] = s; }
  __syncthreads();
  if (tid == 0) {
    float M2 = redm[0], S2 = reds[0];
#pragma unroll
    for (int w = 1; w < 4; ++w) {
      float om = redm[w], os = reds[w];
      float nm = fmaxf(M2, om);
      S2 = S2 * __expf(M2 - nm) + os * __expf(om - nm);
      M2 = nm;
    }
    float lt = logits[(size_t)row * Vc + targets[row]];
    rowloss[row] = -(lt - M2 - logf(S2));
  }
}

__global__ __launch_bounds__(1024) void lossred_k(const float* __restrict__ rowloss,
                                                  float* __restrict__ outp) {
  __shared__ float red[16];
  float s = 0.f;
  for (int i = threadIdx.x; i < Mc; i += 1024) s += rowloss[i];
  s = wave_sum(s);
  if ((threadIdx.x & 63) == 0) red[threadIdx.x >> 6] = s;
  __syncthreads();
  if (threadIdx.x == 0) {
    float tot = 0.f;
#pragma unroll
    for (int i = 0; i < 16; ++i) tot += red[i];
    outp[0] = tot * (1.0f / (float)Mc);
  }
}

}  // namespace

extern "C" void kernel_launch(void* const* d_in, const int* in_sizes, int n_in,
                              void* d_out, int out_size, void* d_ws, size_t ws_size,
                              hipStream_t stream) {
  const int*   tokens  = (const int*)d_in[0];
  const int*   targets = (const int*)d_in[1];
  const float* tok_emb = (const float*)d_in[2];
  const float* pet     = (const float*)d_in[3];
  const float* wq      = (const float*)d_in[4];
  const float* wk      = (const float*)d_in[5];
  const float* wv      = (const float*)d_in[6];
  const float* w_proj  = (const float*)d_in[7];
  const float* b_proj  = (const float*)d_in[8];
  const float* ln1_g   = (const float*)d_in[9];
  const float* ln1_b   = (const float*)d_in[10];
  const float* ln2_g   = (const float*)d_in[11];
  const float* ln2_b   = (const float*)d_in[12];
  const float* w_ff1   = (const float*)d_in[13];
  const float* b_ff1   = (const float*)d_in[14];
  const float* w_ff2   = (const float*)d_in[15];
  const float* b_ff2   = (const float*)d_in[16];
  const float* lnf_g   = (const float*)d_in[17];
  const float* lnf_b   = (const float*)d_in[18];
  const float* w_out   = (const float*)d_in[19];
  const float* b_out   = (const float*)d_in[20];

  float* out = (float*)d_out;
  char* ob = (char*)d_out;
  // scratch inside dead logits region of d_out (write-before-read per call)
  unsigned short* qkvA  = (unsigned short*)(ob + 0);          // [M][2304] bf16
  unsigned short* attA  = (unsigned short*)(ob + 18874368);   // [M][768]  bf16
  unsigned short* ffhA  = (unsigned short*)(ob + 25165824);   // [M][3072] bf16
  unsigned short* qkvT  = (unsigned short*)(ob + 50331648);   // [L][2304][768]
  unsigned short* projT = (unsigned short*)(ob + 71565312);   // [L][768][768]
  unsigned short* ff1T  = (unsigned short*)(ob + 78643200);   // [L][3072][768]
  unsigned short* ff2T  = (unsigned short*)(ob + 106954752);  // [L][768][3072]
  char* wb = (char*)d_ws;
  float* x = (float*)wb;                                       // 12,582,912 B
  unsigned short* hbuf = (unsigned short*)(wb + 12582912);     //  6,291,456 B
  float* rowloss = (float*)(wb + 18874368);                    //     16,384 B
  unsigned short* woutT = (unsigned short*)(wb + 18890752);    // 49,152,000 B
  float* pbuf = (float*)(wb + 68042752);                       //  4,096,000 B
  const bool wfit = ws_size >= (size_t)18890752 + 49152000;
  const bool pfit = ws_size >= (size_t)68042752 + 4096000;

  qcvt_k<<<dim3(12, 3 * Lc * Hc), 256, 0, stream>>>(wq, wk, wv, qkvT);
  tcvt_k<<<dim3(12, 12, 6), 256, 0, stream>>>(w_proj, projT, 768, 768,
                                              (size_t)589824, (size_t)589824);
  tcvt_k<<<dim3(48, 12, 6), 256, 0, stream>>>(w_ff1, ff1T, 768, 3072,
                                              (size_t)768 * 3072, (size_t)768 * 3072);
  tcvt_k<<<dim3(12, 48, 6), 256, 0, stream>>>(w_ff2, ff2T, 3072, 768,
                                              (size_t)768 * 3072, (size_t)768 * 3072);
  if (wfit)
    tcvt_k<<<dim3(500, 12, 1), 256, 0, stream>>>(w_out, woutT, 768, 32000, 0, 0);

  embed_k<<<(Mc * Ec) / 256, 256, 0, stream>>>(tokens, tok_emb, pet, x);

  for (int l = 0; l < Lc; ++l) {
    ln_k<<<Mc, 256, 0, stream>>>(x, ln1_g + (size_t)l * Ec, ln1_b + (size_t)l * Ec, hbuf);
    // qkv: 128x64 tile, grid 1152
    mgemm_k<0, 0, 128, 64, 1><<<dim3(36, 32), 256, 0, stream>>>(
        hbuf, qkvT + (size_t)l * QKVN * Ec, nullptr, qkvA, Mc, QKVN, Ec, nullptr);
    // attention: QBLK=64, 768 blocks -> 3 blocks/CU residency
    fattn2_k<1><<<dim3(Tc / 64, Bc * Hc), 256, 0, stream>>>(qkvA, attA);
    // proj: 64x64 tile, grid 768 = 3/CU exact
    mgemm_k<2, 0, 64, 64, 1><<<dim3(12, 64), 256, 0, stream>>>(
        attA, projT + (size_t)l * Ec * Ec, b_proj + (size_t)l * Ec, x, Mc, Ec, Ec, nullptr);
    ln_k<<<Mc, 256, 0, stream>>>(x, ln2_g + (size_t)l * Ec, ln2_b + (size_t)l * Ec, hbuf);
    // ff1: 128x64 tile, grid 1536 = 6/CU exact
    mgemm_k<1, 0, 128, 64, 1><<<dim3(48, 32), 256, 0, stream>>>(
        hbuf, ff1T + (size_t)l * Ec * FFc, b_ff1 + (size_t)l * FFc, ffhA, Mc, FFc, Ec, nullptr);
    // ff2: 64x64 tile, grid 768 = 3/CU exact
    mgemm_k<2, 0, 64, 64, 1><<<dim3(12, 64), 256, 0, stream>>>(
        ffhA, ff2T + (size_t)l * Ec * FFc, b_ff2 + (size_t)l * Ec, x, Mc, Ec, FFc, nullptr);
  }
  ln_k<<<Mc, 256, 0, stream>>>(x, lnf_g, lnf_b, hbuf);
  // logits GEMM: round-15 config (bm-fastest dedup, T2, PIPE=2, 128x128)
  // + cheap fused sum-exp partials when pbuf fits
  if (wfit && pfit) {
    mgemm_k<4, 0, 128, 128, 32><<<dim3(32, 250, 1), 256, 0, stream>>>(
        hbuf, woutT, b_out, out, Mc, Vc, Ec, pbuf);
    lossfin_k<<<Mc / 4, 256, 0, stream>>>(pbuf, out, targets, rowloss);
  } else if (wfit) {
    mgemm_k<3, 0, 128, 128, 32><<<dim3(32, 250, 1), 256, 0, stream>>>(
        hbuf, woutT, b_out, out, Mc, Vc, Ec, nullptr);
    loss_k<<<Mc, 256, 0, stream>>>(out, targets, rowloss);
  } else {
    mgemm_k<3, 1, 128, 128, 1><<<dim3(250, 32), 256, 0, stream>>>(
        hbuf, w_out, b_out, out, Mc, Vc, Ec, nullptr);
    loss_k<<<Mc, 256, 0, stream>>>(out, targets, rowloss);
  }
  lossred_k<<<1, 1024, 0, stream>>>(rowloss, out + (size_t)Mc * Vc);
}